// Round 1
// baseline (6648.393 us; speedup 1.0000x reference)
//
#include <hip/hip_runtime.h>
#include <hip/hip_bf16.h>

// ---------------------------------------------------------------------------
// RNN: h_{t+1} = tanh(Wx[t] + h_t @ W_h + b_h),  Wx = X @ W_enc + b_enc
// T=512 B=128 D_IN=512 D_H=1024. fp16 MFMA (16x16x32), fp32 accumulate.
// Phase 0: convert/transpose weights to fp16 in ws.
// Phase 1: Wx GEMM (65536x512 @ 512x1024) -> fp16 Wx in ws.
// Phase 2: persistent recurrence kernel: 4 teams x 32 WGs; W_h slice pinned in
//          LDS; team-scoped global barrier per step; h double-buffered in ws.
// ---------------------------------------------------------------------------

typedef _Float16 f16;
typedef f16 f16x8 __attribute__((ext_vector_type(8)));
typedef f16 f16x4 __attribute__((ext_vector_type(4)));
typedef float f32x4 __attribute__((ext_vector_type(4)));

#define T_STEPS 512
#define BATCH   128
#define D_IN    512
#define D_H     1024

// ---- workspace layout (bytes) ----
#define WX_OFF    0                         // fp16 Wx [512][128][1024] = 134217728
#define WENC_OFF  (134217728)               // fp16 W_encT [1024][512]  = 1048576
#define WH_OFF    (WENC_OFF + 1048576)      // fp16 W_hT   [1024][1024] = 2097152
#define HBUF_OFF  (WH_OFF + 2097152)        // fp16 hbuf [2][128][1024] = 524288
#define BAR_OFF   (HBUF_OFF + 524288)       // barrier counters (4096 B)

// ---- recurrence config ----
#define NTEAMS      4
#define WG_PER_TEAM 32
#define BT          32      // batches per team (M)
#define HT          32      // h-columns per WG (N)
#define LDSTR       1032    // fp16 row stride (pad +8 keeps 16B align, spreads banks)

// ===========================================================================
// Phase 0: convert W_enc -> W_encT fp16, W_h -> W_hT fp16, h0 -> hbuf[0] fp16
// ===========================================================================
__global__ void convert_kernel(const float* __restrict__ Wenc,
                               const float* __restrict__ Wh,
                               const float* __restrict__ h0,
                               f16* __restrict__ WencT,
                               f16* __restrict__ WhT,
                               f16* __restrict__ hbuf0) {
    int idx = blockIdx.x * 256 + threadIdx.x;
    if (idx < D_IN * D_H) {                       // 524288: W_enc [512][1024]
        int k = idx >> 10, n = idx & 1023;
        WencT[n * D_IN + k] = (f16)Wenc[idx];
    } else if (idx < D_IN * D_H + D_H * D_H) {    // W_h [1024][1024]
        int j = idx - D_IN * D_H;
        int k = j >> 10, n = j & 1023;
        WhT[n * D_H + k] = (f16)Wh[j];
    } else if (idx < D_IN * D_H + D_H * D_H + BATCH * D_H) {
        int j = idx - (D_IN * D_H + D_H * D_H);
        hbuf0[j] = (f16)h0[j];
    }
}

// ===========================================================================
// Phase 1: Wx = X @ W_enc + b_enc   (M=65536, K=512, N=1024), out fp16
// Tile 128x128, BK=64, 4 waves in 2x2, each wave 64x64 (4x4 MFMA tiles).
// ===========================================================================
__global__ __launch_bounds__(256, 2) void wx_gemm(
        const float* __restrict__ X,       // [65536][512] fp32
        const f16*   __restrict__ WencT,   // [1024][512] fp16 (n-major)
        const float* __restrict__ b_enc,   // [1024]
        f16*         __restrict__ Wx) {    // [65536][1024] fp16
    __shared__ f16 A_lds[128 * 72];
    __shared__ f16 B_lds[128 * 72];

    const int m0 = blockIdx.x * 128;
    const int n0 = blockIdx.y * 128;
    const int tid = threadIdx.x;
    const int wave = tid >> 6, lane = tid & 63;
    const int q = lane >> 4, r = lane & 15;
    const int wm = wave >> 1, wn = wave & 1;

    f32x4 acc[4][4] = {};

    for (int kb = 0; kb < D_IN; kb += 64) {
        // stage A: 128 rows x 64 k fp32 -> fp16 LDS
        #pragma unroll
        for (int i = 0; i < 8; ++i) {
            int vec = tid + i * 256;           // 2048 float4
            int m = vec >> 4, k4 = vec & 15;
            float4 f = *(const float4*)(X + (size_t)(m0 + m) * D_IN + kb + k4 * 4);
            f16x4 h4;
            h4[0] = (f16)f.x; h4[1] = (f16)f.y; h4[2] = (f16)f.z; h4[3] = (f16)f.w;
            *(f16x4*)(A_lds + m * 72 + k4 * 4) = h4;
        }
        // stage B: 128 n-rows x 64 k fp16 (already transposed)
        #pragma unroll
        for (int i = 0; i < 4; ++i) {
            int vec = tid + i * 256;           // 1024 vec8
            int n = vec >> 3, k8 = vec & 7;
            f16x8 v = *(const f16x8*)(WencT + (size_t)(n0 + n) * D_IN + kb + k8 * 8);
            *(f16x8*)(B_lds + n * 72 + k8 * 8) = v;
        }
        __syncthreads();
        #pragma unroll
        for (int ks = 0; ks < 2; ++ks) {
            f16x8 a[4], b[4];
            #pragma unroll
            for (int i = 0; i < 4; ++i)
                a[i] = *(const f16x8*)(A_lds + (wm * 64 + i * 16 + r) * 72 + ks * 32 + q * 8);
            #pragma unroll
            for (int j = 0; j < 4; ++j)
                b[j] = *(const f16x8*)(B_lds + (wn * 64 + j * 16 + r) * 72 + ks * 32 + q * 8);
            #pragma unroll
            for (int i = 0; i < 4; ++i)
                #pragma unroll
                for (int j = 0; j < 4; ++j)
                    acc[i][j] = __builtin_amdgcn_mfma_f32_16x16x32_f16(a[i], b[j], acc[i][j], 0, 0, 0);
        }
        __syncthreads();
    }
    // epilogue: + b_enc, cast fp16, store
    #pragma unroll
    for (int j = 0; j < 4; ++j) {
        int col = n0 + wn * 64 + j * 16 + r;
        float be = b_enc[col];
        #pragma unroll
        for (int i = 0; i < 4; ++i) {
            int row = m0 + wm * 64 + i * 16 + q * 4;
            #pragma unroll
            for (int ii = 0; ii < 4; ++ii)
                Wx[(size_t)(row + ii) * D_H + col] = (f16)(acc[i][j][ii] + be);
        }
    }
}

// ===========================================================================
// Phase 2: the scan. 128 WGs x 256 threads. 4 teams x 32 WGs.
// WG: W_hT cols [c0,c0+32) pinned in LDS; per step stage team h, 32 MFMAs/wave.
// ===========================================================================
extern __shared__ char smem_raw[];

__global__ __launch_bounds__(256, 1) void rnn_steps(
        const f16*  __restrict__ WhT,    // [1024][1024] fp16 n-major
        const f16*  __restrict__ Wx,     // [512][128][1024] fp16
        const float* __restrict__ b_h,   // [1024]
        f16*        __restrict__ hbuf,   // [2][128][1024] fp16
        float*      __restrict__ out,    // [128][1024] fp32
        unsigned*   __restrict__ bar) {
    f16* w_lds = (f16*)smem_raw;                  // [HT][LDSTR]
    f16* h_lds = (f16*)smem_raw + HT * LDSTR;     // [BT][LDSTR]

    const int team = blockIdx.x / WG_PER_TEAM;
    const int wg   = blockIdx.x % WG_PER_TEAM;
    const int b0 = team * BT;
    const int c0 = wg * HT;
    const int tid = threadIdx.x;
    const int wave = tid >> 6, lane = tid & 63;
    const int q = lane >> 4, r = lane & 15;
    const int mt = wave >> 1, nt = wave & 1;      // 2x2 wave grid over 32x32 tile

    unsigned* cnt = bar + team * 64;              // 256B apart per team
    unsigned* gen = bar + team * 64 + 32;

    // pin W_h slice: 32 n-rows x 1024 k
    #pragma unroll
    for (int i = 0; i < 16; ++i) {
        int vec = tid + i * 256;                  // 4096 vec8
        int n = vec >> 7, k8 = vec & 127;
        f16x8 v = *(const f16x8*)(WhT + (size_t)(c0 + n) * D_H + k8 * 8);
        *(f16x8*)(w_lds + n * LDSTR + k8 * 8) = v;
    }
    const int mycol = c0 + nt * 16 + r;
    const float bh = b_h[mycol];
    __syncthreads();

    for (int t = 0; t < T_STEPS; ++t) {
        const f16* hc = hbuf + (t & 1) * (BATCH * D_H);
        f16*       hn = hbuf + ((t + 1) & 1) * (BATCH * D_H);

        // prefetch this lane's Wx[t] values (used in epilogue)
        f16 wx[4];
        #pragma unroll
        for (int i = 0; i < 4; ++i)
            wx[i] = Wx[(size_t)t * (BATCH * D_H) + (size_t)(b0 + mt * 16 + q * 4 + i) * D_H + mycol];

        // stage team h: 32 rows x 1024 fp16
        #pragma unroll
        for (int i = 0; i < 16; ++i) {
            int vec = tid + i * 256;
            int m = vec >> 7, k8 = vec & 127;
            f16x8 v = *(const f16x8*)(hc + (size_t)(b0 + m) * D_H + k8 * 8);
            *(f16x8*)(h_lds + m * LDSTR + k8 * 8) = v;
        }
        __syncthreads();

        f32x4 acc0 = {0.f, 0.f, 0.f, 0.f}, acc1 = {0.f, 0.f, 0.f, 0.f};
        #pragma unroll
        for (int kk = 0; kk < 32; kk += 2) {
            f16x8 a0 = *(const f16x8*)(h_lds + (mt * 16 + r) * LDSTR + kk * 32 + q * 8);
            f16x8 b0f = *(const f16x8*)(w_lds + (nt * 16 + r) * LDSTR + kk * 32 + q * 8);
            acc0 = __builtin_amdgcn_mfma_f32_16x16x32_f16(a0, b0f, acc0, 0, 0, 0);
            f16x8 a1 = *(const f16x8*)(h_lds + (mt * 16 + r) * LDSTR + (kk + 1) * 32 + q * 8);
            f16x8 b1f = *(const f16x8*)(w_lds + (nt * 16 + r) * LDSTR + (kk + 1) * 32 + q * 8);
            acc1 = __builtin_amdgcn_mfma_f32_16x16x32_f16(a1, b1f, acc1, 0, 0, 0);
        }

        // epilogue: tanh(acc + Wx + b_h) -> fp16 h_next (+ fp32 out at last step)
        #pragma unroll
        for (int i = 0; i < 4; ++i) {
            int b = b0 + mt * 16 + q * 4 + i;
            float v = acc0[i] + acc1[i] + (float)wx[i] + bh;
            float th = tanhf(v);
            hn[(size_t)b * D_H + mycol] = (f16)th;
            if (t == T_STEPS - 1) out[(size_t)b * D_H + mycol] = th;
        }

        // team barrier (monotonic count, no reset)
        __syncthreads();   // drains vmcnt: all WG stores at least in L2
        if (tid == 0) {
            __threadfence();  // agent release: write back L2 so other XCDs see h
            unsigned prev = __hip_atomic_fetch_add(cnt, 1u, __ATOMIC_ACQ_REL,
                                                   __HIP_MEMORY_SCOPE_AGENT);
            if (prev == (unsigned)((t + 1) * WG_PER_TEAM - 1)) {
                __hip_atomic_store(gen, (unsigned)(t + 1), __ATOMIC_RELEASE,
                                   __HIP_MEMORY_SCOPE_AGENT);
            } else {
                while (__hip_atomic_load(gen, __ATOMIC_RELAXED,
                                         __HIP_MEMORY_SCOPE_AGENT) < (unsigned)(t + 1)) {
                    __builtin_amdgcn_s_sleep(1);
                }
                __threadfence();  // agent acquire: invalidate stale lines
            }
        }
        __syncthreads();
    }
}

// ===========================================================================
extern "C" void kernel_launch(void* const* d_in, const int* in_sizes, int n_in,
                              void* d_out, int out_size, void* d_ws, size_t ws_size,
                              hipStream_t stream) {
    const float* X     = (const float*)d_in[0];   // [512][128][512]
    const float* h0    = (const float*)d_in[1];   // [128][1024]
    const float* Wenc  = (const float*)d_in[2];   // [512][1024]
    const float* b_enc = (const float*)d_in[3];   // [1024]
    const float* Wh    = (const float*)d_in[4];   // [1024][1024]
    const float* b_h   = (const float*)d_in[5];   // [1024]
    float* out = (float*)d_out;

    char* ws = (char*)d_ws;
    f16* Wx16    = (f16*)(ws + WX_OFF);
    f16* WencT16 = (f16*)(ws + WENC_OFF);
    f16* WhT16   = (f16*)(ws + WH_OFF);
    f16* hbuf    = (f16*)(ws + HBUF_OFF);
    unsigned* bar = (unsigned*)(ws + BAR_OFF);

    // zero barrier counters (ws is poisoned before every call)
    hipMemsetAsync(bar, 0, 4096, stream);

    // Phase 0: converts/transposes
    int total = D_IN * D_H + D_H * D_H + BATCH * D_H;   // 1703936
    convert_kernel<<<(total + 255) / 256, 256, 0, stream>>>(Wenc, Wh, h0,
                                                            WencT16, WhT16, hbuf);

    // Phase 1: Wx GEMM
    wx_gemm<<<dim3(65536 / 128, D_H / 128), 256, 0, stream>>>(X, WencT16, b_enc, Wx16);

    // Phase 2: recurrence (132096 B dynamic LDS > 64KB default -> raise cap)
    const int lds_bytes = (HT + BT) * LDSTR * 2;   // 132096
    hipFuncSetAttribute((const void*)rnn_steps,
                        hipFuncAttributeMaxDynamicSharedMemorySize, lds_bytes);
    rnn_steps<<<NTEAMS * WG_PER_TEAM, 256, lds_bytes, stream>>>(
        WhT16, Wx16, b_h, hbuf, out, bar);
}

// Round 2
// 5377.996 us; speedup vs baseline: 1.2362x; 1.2362x over previous
//
#include <hip/hip_runtime.h>
#include <hip/hip_bf16.h>

// ---------------------------------------------------------------------------
// RNN: h_{t+1} = tanh(Wx[t] + h_t @ W_h + b_h),  Wx = X @ W_enc + b_enc
// T=512 B=128 D_IN=512 D_H=1024. fp16 MFMA (16x16x32), fp32 accumulate.
// Phase 0: convert/transpose weights to fp16 in ws.
// Phase 1: Wx GEMM (65536x512 @ 512x1024) -> fp16 Wx in ws.
// Phase 2: persistent recurrence: 4 teams x 32 WGs; W_h slice pinned in LDS.
//   Cross-WG h exchange via RELAXED AGENT-SCOPE ATOMICS (sc0/sc1, bypass the
//   non-coherent per-XCD L2) -> no __threadfence (no buffer_wbl2/buffer_inv,
//   which caused 520 MB of HBM refetch + ~12 us/step in R1).
//   Sync: per-WG monotonic flag slot + wave-0 ballot poll (no serialized RMW).
// ---------------------------------------------------------------------------

typedef _Float16 f16;
typedef f16 f16x8 __attribute__((ext_vector_type(8)));
typedef f16 f16x4 __attribute__((ext_vector_type(4)));
typedef float f32x4 __attribute__((ext_vector_type(4)));
typedef unsigned long long u64;

#define T_STEPS 512
#define BATCH   128
#define D_IN    512
#define D_H     1024

// ---- workspace layout (bytes) ----
#define WX_OFF    0                         // fp16 Wx [512][128][1024] = 134217728
#define WENC_OFF  (134217728)               // fp16 W_encT [1024][512]  = 1048576
#define WH_OFF    (WENC_OFF + 1048576)      // fp16 W_hT   [1024][1024] = 2097152
#define HBUF_OFF  (WH_OFF + 2097152)        // fp16 hbuf [2][128][1024] = 524288
#define BAR_OFF   (HBUF_OFF + 524288)       // flag slots: 4*32*64B = 8192 B

// ---- recurrence config ----
#define NTEAMS      4
#define WG_PER_TEAM 32
#define BT          32      // batches per team (M)
#define HT          32      // h-columns per WG (N)
#define LDSTR       1032    // fp16 row stride (pad +8 keeps 16B align)
#define TSTR        36      // transpose-tile stride (fp16)

// ---- relaxed agent-scope atomic helpers (cache-bypassing, no fences) ----
__device__ __forceinline__ u64 atom_ld8(const void* p) {
    return __hip_atomic_load((const u64*)p, __ATOMIC_RELAXED, __HIP_MEMORY_SCOPE_AGENT);
}
__device__ __forceinline__ void atom_st8(void* p, u64 v) {
    __hip_atomic_store((u64*)p, v, __ATOMIC_RELAXED, __HIP_MEMORY_SCOPE_AGENT);
}
__device__ __forceinline__ unsigned atom_ld4(const unsigned* p) {
    return __hip_atomic_load(p, __ATOMIC_RELAXED, __HIP_MEMORY_SCOPE_AGENT);
}
__device__ __forceinline__ void atom_st4(unsigned* p, unsigned v) {
    __hip_atomic_store(p, v, __ATOMIC_RELAXED, __HIP_MEMORY_SCOPE_AGENT);
}

// ===========================================================================
// Phase 0: convert W_enc -> W_encT fp16, W_h -> W_hT fp16, h0 -> hbuf[0] fp16
// ===========================================================================
__global__ void convert_kernel(const float* __restrict__ Wenc,
                               const float* __restrict__ Wh,
                               const float* __restrict__ h0,
                               f16* __restrict__ WencT,
                               f16* __restrict__ WhT,
                               f16* __restrict__ hbuf0) {
    int idx = blockIdx.x * 256 + threadIdx.x;
    if (idx < D_IN * D_H) {                       // 524288: W_enc [512][1024]
        int k = idx >> 10, n = idx & 1023;
        WencT[n * D_IN + k] = (f16)Wenc[idx];
    } else if (idx < D_IN * D_H + D_H * D_H) {    // W_h [1024][1024]
        int j = idx - D_IN * D_H;
        int k = j >> 10, n = j & 1023;
        WhT[n * D_H + k] = (f16)Wh[j];
    } else if (idx < D_IN * D_H + D_H * D_H + BATCH * D_H) {
        int j = idx - (D_IN * D_H + D_H * D_H);
        hbuf0[j] = (f16)h0[j];
    }
}

// ===========================================================================
// Phase 1: Wx = X @ W_enc + b_enc   (M=65536, K=512, N=1024), out fp16
// ===========================================================================
__global__ __launch_bounds__(256, 2) void wx_gemm(
        const float* __restrict__ X,       // [65536][512] fp32
        const f16*   __restrict__ WencT,   // [1024][512] fp16 (n-major)
        const float* __restrict__ b_enc,   // [1024]
        f16*         __restrict__ Wx) {    // [65536][1024] fp16
    __shared__ f16 A_lds[128 * 72];
    __shared__ f16 B_lds[128 * 72];

    const int m0 = blockIdx.x * 128;
    const int n0 = blockIdx.y * 128;
    const int tid = threadIdx.x;
    const int wave = tid >> 6, lane = tid & 63;
    const int q = lane >> 4, r = lane & 15;
    const int wm = wave >> 1, wn = wave & 1;

    f32x4 acc[4][4] = {};

    for (int kb = 0; kb < D_IN; kb += 64) {
        #pragma unroll
        for (int i = 0; i < 8; ++i) {
            int vec = tid + i * 256;           // 2048 float4
            int m = vec >> 4, k4 = vec & 15;
            float4 f = *(const float4*)(X + (size_t)(m0 + m) * D_IN + kb + k4 * 4);
            f16x4 h4;
            h4[0] = (f16)f.x; h4[1] = (f16)f.y; h4[2] = (f16)f.z; h4[3] = (f16)f.w;
            *(f16x4*)(A_lds + m * 72 + k4 * 4) = h4;
        }
        #pragma unroll
        for (int i = 0; i < 4; ++i) {
            int vec = tid + i * 256;           // 1024 vec8
            int n = vec >> 3, k8 = vec & 7;
            f16x8 v = *(const f16x8*)(WencT + (size_t)(n0 + n) * D_IN + kb + k8 * 8);
            *(f16x8*)(B_lds + n * 72 + k8 * 8) = v;
        }
        __syncthreads();
        #pragma unroll
        for (int ks = 0; ks < 2; ++ks) {
            f16x8 a[4], b[4];
            #pragma unroll
            for (int i = 0; i < 4; ++i)
                a[i] = *(const f16x8*)(A_lds + (wm * 64 + i * 16 + r) * 72 + ks * 32 + q * 8);
            #pragma unroll
            for (int j = 0; j < 4; ++j)
                b[j] = *(const f16x8*)(B_lds + (wn * 64 + j * 16 + r) * 72 + ks * 32 + q * 8);
            #pragma unroll
            for (int i = 0; i < 4; ++i)
                #pragma unroll
                for (int j = 0; j < 4; ++j)
                    acc[i][j] = __builtin_amdgcn_mfma_f32_16x16x32_f16(a[i], b[j], acc[i][j], 0, 0, 0);
        }
        __syncthreads();
    }
    #pragma unroll
    for (int j = 0; j < 4; ++j) {
        int col = n0 + wn * 64 + j * 16 + r;
        float be = b_enc[col];
        #pragma unroll
        for (int i = 0; i < 4; ++i) {
            int row = m0 + wm * 64 + i * 16 + q * 4;
            #pragma unroll
            for (int ii = 0; ii < 4; ++ii)
                Wx[(size_t)(row + ii) * D_H + col] = (f16)(acc[i][j][ii] + be);
        }
    }
}

// ===========================================================================
// Phase 2: the scan. 128 WGs x 256 threads. 4 teams x 32 WGs.
// ===========================================================================
extern __shared__ char smem_raw[];

__global__ __launch_bounds__(256, 1) void rnn_steps(
        const f16*  __restrict__ WhT,    // [1024][1024] fp16 n-major
        const f16*  __restrict__ Wx,     // [512][128][1024] fp16
        const float* __restrict__ b_h,   // [1024]
        f16*        __restrict__ hbuf,   // [2][128][1024] fp16
        float*      __restrict__ out,    // [128][1024] fp32
        unsigned*   __restrict__ flags) {// [4][32] slots, 64B apart
    f16* w_lds = (f16*)smem_raw;                        // [HT][LDSTR]
    f16* h_lds = (f16*)smem_raw + HT * LDSTR;           // [BT][LDSTR]
    f16* t_lds = (f16*)smem_raw + (HT + BT) * LDSTR;    // [32][TSTR] transpose tile

    const int team = blockIdx.x / WG_PER_TEAM;
    const int wg   = blockIdx.x % WG_PER_TEAM;
    const int b0 = team * BT;
    const int c0 = wg * HT;
    const int tid = threadIdx.x;
    const int wave = tid >> 6, lane = tid & 63;
    const int q = lane >> 4, r = lane & 15;
    const int mt = wave >> 1, nt = wave & 1;            // 2x2 wave grid, 32x32 tile

    unsigned* myflag = flags + (team * WG_PER_TEAM + wg) * 16;   // 64B apart
    unsigned* teamflags = flags + team * WG_PER_TEAM * 16;

    // pin W_h slice: 32 n-rows x 1024 k
    #pragma unroll
    for (int i = 0; i < 16; ++i) {
        int vec = tid + i * 256;                        // 4096 vec8
        int n = vec >> 7, k8 = vec & 127;
        f16x8 v = *(const f16x8*)(WhT + (size_t)(c0 + n) * D_H + k8 * 8);
        *(f16x8*)(w_lds + n * LDSTR + k8 * 8) = v;
    }
    const int mycol = c0 + nt * 16 + r;
    const float bh = b_h[mycol];
    const int bl = tid >> 3, cg = tid & 7;              // transpose-read mapping
    __syncthreads();

    for (int t = 0; t < T_STEPS; ++t) {
        const f16* hc = hbuf + (t & 1) * (BATCH * D_H);
        f16*       hn = hbuf + ((t + 1) & 1) * (BATCH * D_H);

        // prefetch this lane's Wx[t] (independent of h arrival; hides HBM latency)
        f16 wx[4];
        #pragma unroll
        for (int i = 0; i < 4; ++i)
            wx[i] = Wx[(size_t)t * (BATCH * D_H) + (size_t)(b0 + mt * 16 + q * 4 + i) * D_H + mycol];

        // stage team h: 32 rows x 1024 fp16 via relaxed agent atomic 8B loads
        #pragma unroll
        for (int i = 0; i < 32; ++i) {
            int vec = tid + i * 256;                    // 0..8191 chunks of 8B
            int m = vec >> 8, c = vec & 255;
            u64 v = atom_ld8(hc + (size_t)(b0 + m) * D_H + c * 4);
            *(u64*)(h_lds + m * LDSTR + c * 4) = v;
        }
        __syncthreads();

        f32x4 acc0 = {0.f, 0.f, 0.f, 0.f}, acc1 = {0.f, 0.f, 0.f, 0.f};
        #pragma unroll
        for (int kk = 0; kk < 32; kk += 2) {
            f16x8 a0 = *(const f16x8*)(h_lds + (mt * 16 + r) * LDSTR + kk * 32 + q * 8);
            f16x8 b0f = *(const f16x8*)(w_lds + (nt * 16 + r) * LDSTR + kk * 32 + q * 8);
            acc0 = __builtin_amdgcn_mfma_f32_16x16x32_f16(a0, b0f, acc0, 0, 0, 0);
            f16x8 a1 = *(const f16x8*)(h_lds + (mt * 16 + r) * LDSTR + (kk + 1) * 32 + q * 8);
            f16x8 b1f = *(const f16x8*)(w_lds + (nt * 16 + r) * LDSTR + (kk + 1) * 32 + q * 8);
            acc1 = __builtin_amdgcn_mfma_f32_16x16x32_f16(a1, b1f, acc1, 0, 0, 0);
        }

        // epilogue: tanh(acc + Wx + b_h) -> transpose tile (col-major, so the
        // re-reader owns 4 CONTIGUOUS columns of one batch -> 8B atomic store)
        f16x4 hv;
        #pragma unroll
        for (int i = 0; i < 4; ++i) {
            float v = acc0[i] + acc1[i] + (float)wx[i] + bh;
            hv[i] = (f16)tanhf(v);
        }
        *(f16x4*)(t_lds + (nt * 16 + r) * TSTR + mt * 16 + q * 4) = hv;
        __syncthreads();

        // re-read transposed: thread owns (batch bl, cols cg*4..cg*4+3)
        f16x4 pk;
        #pragma unroll
        for (int j = 0; j < 4; ++j)
            pk[j] = t_lds[(cg * 4 + j) * TSTR + bl];
        atom_st8(hn + (size_t)(b0 + bl) * D_H + c0 + cg * 4,
                 __builtin_bit_cast(u64, pk));
        if (t == T_STEPS - 1) {
            float4 o;
            o.x = (float)pk[0]; o.y = (float)pk[1];
            o.z = (float)pk[2]; o.w = (float)pk[3];
            *(float4*)(out + (size_t)(b0 + bl) * D_H + c0 + cg * 4) = o;
        }

        if (t < T_STEPS - 1) {
            // team barrier: per-WG monotonic flag + wave-0 ballot poll.
            __syncthreads();   // compiler drains vmcnt(0) before s_barrier ->
                               // all 8B h stores are at the coherent point.
            if (tid == 0) atom_st4(myflag, (unsigned)(t + 1));
            if (tid < 64) {
                bool mine = (lane < WG_PER_TEAM);
                const unsigned* slot = teamflags + (mine ? lane : 0) * 16;
                unsigned v = mine ? atom_ld4(slot) : 0xFFFFFFFFu;
                while (__ballot(v < (unsigned)(t + 1))) {
                    __builtin_amdgcn_s_sleep(1);
                    v = mine ? atom_ld4(slot) : 0xFFFFFFFFu;
                }
            }
            __syncthreads();
        }
    }
}

// ===========================================================================
extern "C" void kernel_launch(void* const* d_in, const int* in_sizes, int n_in,
                              void* d_out, int out_size, void* d_ws, size_t ws_size,
                              hipStream_t stream) {
    const float* X     = (const float*)d_in[0];   // [512][128][512]
    const float* h0    = (const float*)d_in[1];   // [128][1024]
    const float* Wenc  = (const float*)d_in[2];   // [512][1024]
    const float* b_enc = (const float*)d_in[3];   // [1024]
    const float* Wh    = (const float*)d_in[4];   // [1024][1024]
    const float* b_h   = (const float*)d_in[5];   // [1024]
    float* out = (float*)d_out;

    char* ws = (char*)d_ws;
    f16* Wx16    = (f16*)(ws + WX_OFF);
    f16* WencT16 = (f16*)(ws + WENC_OFF);
    f16* WhT16   = (f16*)(ws + WH_OFF);
    f16* hbuf    = (f16*)(ws + HBUF_OFF);
    unsigned* flags = (unsigned*)(ws + BAR_OFF);

    // zero flag slots (ws is re-poisoned to 0xAA before every timed call)
    hipMemsetAsync(flags, 0, 8192, stream);

    // Phase 0: converts/transposes
    int total = D_IN * D_H + D_H * D_H + BATCH * D_H;   // 1703936
    convert_kernel<<<(total + 255) / 256, 256, 0, stream>>>(Wenc, Wh, h0,
                                                            WencT16, WhT16, hbuf);

    // Phase 1: Wx GEMM
    wx_gemm<<<dim3(65536 / 128, D_H / 128), 256, 0, stream>>>(X, WencT16, b_enc, Wx16);

    // Phase 2: recurrence. LDS = (32+32)*1032*2 + 32*36*2 = 134400 B
    const int lds_bytes = (HT + BT) * LDSTR * 2 + 32 * TSTR * 2;
    hipFuncSetAttribute((const void*)rnn_steps,
                        hipFuncAttributeMaxDynamicSharedMemorySize, lds_bytes);
    rnn_steps<<<NTEAMS * WG_PER_TEAM, 256, lds_bytes, stream>>>(
        WhT16, Wx16, b_h, hbuf, out, flags);
}